// Round 3
// baseline (958.087 us; speedup 1.0000x reference)
//
#include <hip/hip_runtime.h>
#include <stdint.h>

#define TT_ 4096
#define CC_ 192
#define TILE_ 64
#define HALO_ 13
#define TW_ 90
#define HS_ 104     // H row stride (bf16)
#define YTS_ 200    // YT row stride (bf16)
#define NT_ 1024

typedef float f32x4 __attribute__((ext_vector_type(4)));
typedef short s16x4 __attribute__((ext_vector_type(4)));
typedef short s16x8 __attribute__((ext_vector_type(8)));
typedef uint32_t ui32x4 __attribute__((ext_vector_type(4)));

__device__ __forceinline__ float bf2f(short s){
  uint32_t u = ((uint32_t)(uint16_t)s) << 16;
  float f; __builtin_memcpy(&f, &u, 4); return f;
}
__device__ __forceinline__ float bfhalf(uint32_t u, int hi){
  uint32_t v = hi ? (u & 0xFFFF0000u) : (u << 16);
  float f; __builtin_memcpy(&f, &v, 4); return f;
}
__device__ __forceinline__ short f2bf(float f){
  uint32_t u; __builtin_memcpy(&u, &f, 4);
  u += 0x7FFFu + ((u >> 16) & 1u);   // RNE
  return (short)(u >> 16);
}
// tanh-form GELU: x*sigmoid(1.5957691*(x+0.044715*x^3))
__device__ __forceinline__ float gelu_f(float x){
  float t = x*x;
  float p = x*__builtin_fmaf(t, 0.0713548162f, 1.5957691216f);
  float e = __expf(-p);
  return x * __builtin_amdgcn_rcpf(1.0f + e);
}

// ---- depthwise conv, transposed write: H[c][j] (bf16, pre-masked) -> YT[j][c]
template<int D>
__device__ __forceinline__ void dw_pass(const short* __restrict__ Hs, short* __restrict__ YTs,
    const float* __restrict__ sw, const float* __restrict__ sb,
    int jlo, int jhi, int tid){
  constexpr int WO = (D==9) ? 16 : 8;
  constexpr int NW = (D==9) ? 5 : 3;   // s16x8 window loads per channel row
  for (int g = tid; g < 96*12; g += NT_){
    int cg = g % 96, jg = g / 96;
    int j0 = jg*8;
    if (j0 + 8 <= jlo || j0 >= jhi) continue;
    int c0 = cg*2;
    uint32_t pk[8];
    #pragma unroll
    for (int cc = 0; cc < 2; ++cc){
      int c = c0 + cc;
      float w0 = sw[c*3+0], w1 = sw[c*3+1], w2 = sw[c*3+2], bb = sb[c];
      uint32_t wp[NW*4];
      const uint32_t* hrow = (const uint32_t*)(Hs + c*HS_ + j0 - WO);  // 16B aligned
      #pragma unroll
      for (int u = 0; u < NW; ++u){
        ui32x4 t = *(const ui32x4*)(hrow + u*4);
        wp[u*4+0]=t[0]; wp[u*4+1]=t[1]; wp[u*4+2]=t[2]; wp[u*4+3]=t[3];
      }
      #pragma unroll
      for (int j = 0; j < 8; ++j){
        float t0 = bfhalf(wp[(WO+j-D)>>1], (WO+j-D)&1);
        float t1 = bfhalf(wp[(WO+j)>>1],   (WO+j)&1);
        float t2 = bfhalf(wp[(WO+j+D)>>1], (WO+j+D)&1);
        float v = __builtin_fmaf(w0,t0, __builtin_fmaf(w1,t1, __builtin_fmaf(w2,t2, bb)));
        uint32_t hb = (uint32_t)(uint16_t)f2bf(v);
        if (cc==0) pk[j] = hb; else pk[j] |= (hb << 16);
      }
    }
    #pragma unroll
    for (int j = 0; j < 8; ++j)
      *(uint32_t*)(YTs + (j0+j)*YTS_ + c0) = pk[j];   // lanes: c fastest -> conflict-free
  }
}

// ---- per-time-row LN stats over 192 cols of YT; 4 threads/row, quad shuffle
__device__ __forceinline__ void ln_stats(const short* __restrict__ YTs, float* __restrict__ SM,
                                         float* __restrict__ SR, int jlo, int jhi, int tid){
  if (tid < 384){
    int row = tid >> 2, qtr = tid & 3;
    if (row >= jlo && row < jhi){
      const short* yr = YTs + row*YTS_ + qtr*48;
      float s0 = 0.f, s1 = 0.f, q0 = 0.f, q1 = 0.f;
      #pragma unroll
      for (int u=0;u<6;++u){
        s16x8 v = *(const s16x8*)(yr + u*8);
        #pragma unroll
        for (int e=0;e<4;e++){ float f=bf2f(v[e]); s0 += f; q0 = __builtin_fmaf(f,f,q0); }
        #pragma unroll
        for (int e=4;e<8;e++){ float f=bf2f(v[e]); s1 += f; q1 = __builtin_fmaf(f,f,q1); }
      }
      float s = s0+s1, q = q0+q1;
      s += __shfl_xor(s,1); q += __shfl_xor(q,1);
      s += __shfl_xor(s,2); q += __shfl_xor(q,2);
      if (qtr==0){
        float mean = s*(1.f/192.f);
        float var = fmaxf(q*(1.f/192.f) - mean*mean, 0.f);
        SM[row]=mean; SR[row]=rsqrtf(var+1e-5f);
      }
    }
  }
}

__global__ __launch_bounds__(1024, 8)
void convflow_main(
    const float* __restrict__ x, const float* __restrict__ xmask,
    const float* __restrict__ pre_w, const float* __restrict__ pre_b,
    const float* __restrict__ sep_w, const float* __restrict__ sep_b,
    const float* __restrict__ pw_b,
    const float* __restrict__ ln1_g, const float* __restrict__ ln1_b,
    const float* __restrict__ ln2_g, const float* __restrict__ ln2_b,
    const float* __restrict__ proj_b,
    const short* __restrict__ Wbf, const short* __restrict__ Pbf,
    float* __restrict__ out, float* __restrict__ part)
{
  __shared__ __align__(16) char smem_raw[80128];
  float* MB = (float*)(smem_raw + 0);        // [160]: mask at idx j+16, zero outside valid t
  float* XB = (float*)(smem_raw + 640);      // [96]
  float* SM = (float*)(smem_raw + 1024);     // [96]
  float* SR = (float*)(smem_raw + 1408);     // [96]
  short* H  = (short*)(smem_raw + 1792);     // [192][104] bf16, pre-masked
  short* YT = (short*)(smem_raw + 41728);    // [96][200] bf16 (dw-out / LN1-out / GEMM-out)
  float* HP = (float*)(smem_raw + 67328);    // alias YT rows 64..95: [64][33] proj out

  const int tid = threadIdx.x;
  const int b = blockIdx.y, tile = blockIdx.x;
  const int t0 = tile*TILE_ - HALO_;

  // ---- setup mask + x0 window
  for (int idx = tid; idx < 160; idx += NT_){
    int j = idx - 16; int t = t0 + j;
    float m = 0.f;
    if (j >= 0 && j < TW_ && t >= 0 && t < TT_) m = xmask[b*TT_ + t];
    MB[idx] = m;
  }
  if (tid < 96){
    int t = t0 + tid; float v = 0.f;
    if (tid < TW_ && t >= 0 && t < TT_) v = x[(b*2)*TT_ + t];
    XB[tid] = v;
  }
  __syncthreads();

  // ---- h0 = (pre_w*x0 + pre_b)*mask -> H bf16
  for (int g = tid; g < CC_*12; g += NT_){
    int jq = g % 12, c = g / 12;
    float w = pre_w[c], bb = pre_b[c];
    s16x8 hv;
    #pragma unroll
    for (int e=0;e<8;e++){
      int j = jq*8 + e;
      hv[e] = f2bf((w*XB[j] + bb)*MB[16+j]);
    }
    *(s16x8*)(H + c*HS_ + jq*8) = hv;
  }
  __syncthreads();

  // ---- 3 WN layers
  #pragma unroll 1
  for (int li = 0; li < 3; ++li){
    const int jlo = (li==0) ? 1 : ((li==1) ? 4 : 13);
    const int jhi = (li==0) ? 89 : ((li==1) ? 86 : 77);
    const float* sw = sep_w + li*CC_*3;
    const float* sb = sep_b + li*CC_;

    if (li == 0)      dw_pass<1>(H, YT, sw, sb, jlo, jhi, tid);
    else if (li == 1) dw_pass<3>(H, YT, sw, sb, jlo, jhi, tid);
    else              dw_pass<9>(H, YT, sw, sb, jlo, jhi, tid);
    __syncthreads();

    ln_stats(YT, SM, SR, jlo, jhi, tid); __syncthreads();

    // ---- LN1 + gelu in place on YT rows; zero invalid rows
    {
      const float* g1 = ln1_g + li*CC_;
      const float* b1 = ln1_b + li*CC_;
      for (int g = tid; g < 96*24; g += NT_){
        int ch = g % 24, row = g / 24;
        short* p = YT + row*YTS_ + ch*8;
        if (row >= jlo && row < jhi){
          float m = SM[row], r = SR[row];
          s16x8 v = *(s16x8*)p;
          f32x4 ga = *(const f32x4*)&g1[ch*8], gb = *(const f32x4*)&g1[ch*8+4];
          f32x4 ba = *(const f32x4*)&b1[ch*8], bb = *(const f32x4*)&b1[ch*8+4];
          s16x8 o;
          #pragma unroll
          for (int e=0;e<4;e++){
            float val = (bf2f(v[e]) - m)*r*ga[e] + ba[e];
            o[e] = f2bf(gelu_f(val));
          }
          #pragma unroll
          for (int e=4;e<8;e++){
            float val = (bf2f(v[e]) - m)*r*gb[e-4] + bb[e-4];
            o[e] = f2bf(gelu_f(val));
          }
          *(s16x8*)p = o;
        } else {
          s16x8 z = {0,0,0,0,0,0,0,0};
          *(s16x8*)p = z;
        }
      }
    }
    __syncthreads();

    // ---- pointwise 192x192 GEMM in place on YT: 12 waves = 2 M-halves x 6 N-tiles
    {
      int w = tid >> 6, lane = tid & 63, l16 = lane & 15, q = lane >> 4;
      bool act = (w < 12);
      int Nt = w % 6, Mh = w / 6;
      f32x4 acc[6];
      #pragma unroll
      for (int r=0;r<6;r++){ f32x4 z = {0.f,0.f,0.f,0.f}; acc[r] = z; }
      if (act){
        const short* Wl = Wbf + li*CC_*CC_;
        const short* brow = YT + (Nt*16 + l16)*YTS_;
        #pragma unroll
        for (int kk=0;kk<6;++kk){
          s16x8 bv = *(const s16x8*)(brow + kk*32 + q*8);
          #pragma unroll
          for (int r=0;r<6;++r){
            s16x8 av = *(const s16x8*)&Wl[((Mh*6+r)*16 + l16)*CC_ + kk*32 + q*8];
            acc[r] = __builtin_amdgcn_mfma_f32_16x16x32_bf16(av, bv, acc[r], 0, 0, 0);
          }
        }
      }
      __syncthreads();   // all B reads complete before in-place writes
      if (act){
        #pragma unroll
        for (int r=0;r<6;++r){
          int m0 = (Mh*6+r)*16 + q*4;
          f32x4 bias = *(const f32x4*)&pw_b[li*CC_ + m0];
          s16x4 ov;
          #pragma unroll
          for (int e=0;e<4;e++) ov[e] = f2bf(acc[r][e] + bias[e]);
          *(s16x4*)(YT + (Nt*16 + l16)*YTS_ + m0) = ov;
        }
      }
      __syncthreads();
    }

    ln_stats(YT, SM, SR, jlo, jhi, tid); __syncthreads();

    // ---- LN2 + gelu + residual into H (bf16), restricted to [jlo,jhi)
    {
      const float* g2 = ln2_g + li*CC_;
      const float* b2 = ln2_b + li*CC_;
      for (int g = tid; g < 24*48; g += NT_){
        int cgp = g % 48, jg = g / 48;
        int j0 = jg*4, c0 = cgp*4;
        if (j0 + 4 <= jlo || j0 >= jhi) continue;
        f32x4 mv = *(f32x4*)&SM[j0], rv = *(f32x4*)&SR[j0];
        f32x4 mk = *(f32x4*)&MB[16 + j0];
        f32x4 gv = *(const f32x4*)&g2[c0], bv = *(const f32x4*)&b2[c0];
        s16x4 yr[4];
        #pragma unroll
        for (int jj=0;jj<4;++jj) yr[jj] = *(s16x4*)(YT + (j0+jj)*YTS_ + c0);
        #pragma unroll
        for (int cc=0;cc<4;++cc){
          short* hp_ = H + (c0+cc)*HS_ + j0;
          s16x4 hv = *(s16x4*)hp_;
          s16x4 ho;
          #pragma unroll
          for (int jj=0;jj<4;++jj){
            int j = j0 + jj;
            float val = (bf2f(yr[jj][cc]) - mv[jj])*rv[jj]*gv[cc] + bv[cc];
            float hn = (bf2f(hv[jj]) + gelu_f(val))*mk[jj];
            bool ok = (j >= jlo) && (j < jhi);
            ho[jj] = ok ? f2bf(hn) : hv[jj];
          }
          *(s16x4*)hp_ = ho;
        }
      }
    }
    __syncthreads();
  }

  // ---- proj GEMM (32x192 @ 192x64): A from Pbf, B read directly from H columns
  {
    int w = tid >> 6;
    if (w < 4){
      int lane = tid & 63, l16 = lane & 15, q = lane >> 4;
      int mt = w >> 1, ntp = w & 1;
      f32x4 pacc[2];
      { f32x4 z = {0.f,0.f,0.f,0.f}; pacc[0] = z; pacc[1] = z; }
      #pragma unroll
      for (int kk=0;kk<6;++kk){
        s16x8 a = *(const s16x8*)&Pbf[(mt*16 + l16)*CC_ + kk*32 + q*8];
        #pragma unroll
        for (int s=0;s<2;++s){
          int n = (ntp*2+s)*16 + l16;
          s16x8 bvv;
          #pragma unroll
          for (int i=0;i<8;++i)
            bvv[i] = H[(kk*32 + q*8 + i)*HS_ + HALO_ + n];
          pacc[s] = __builtin_amdgcn_mfma_f32_16x16x32_bf16(a, bvv, pacc[s], 0, 0, 0);
        }
      }
      #pragma unroll
      for (int s=0;s<2;++s)
        #pragma unroll
        for (int e=0;e<4;e++){
          int m = mt*16 + q*4 + e;
          if (m < 29){
            int n = (ntp*2+s)*16 + l16;
            HP[n*33 + m] = (pacc[s][e] + proj_b[m]) * MB[16 + HALO_ + n];
          }
        }
    }
  }
  __syncthreads();

  // ---- rational-quadratic spline, one thread per t
  if (tid < 64){
    const int n = tid;
    const int tg = tile*TILE_ + n;
    const float msk = MB[16 + HALO_ + n];
    const float* hp = &HP[n*33];
    const float inv_s = 0.07216878364870323f;  // 1/sqrt(192)
    float uw[10], uh[10], ud9[9];
    #pragma unroll
    for (int k=0;k<10;k++){ uw[k] = hp[k]*inv_s; uh[k] = hp[10+k]*inv_s; }
    #pragma unroll
    for (int k=0;k<9;k++) ud9[k] = hp[20+k];

    float cumw[11], cumh[11];
    {
      float mx = uw[0];
      #pragma unroll
      for (int k=1;k<10;k++) mx = fmaxf(mx, uw[k]);
      float ex[10]; float ss = 0.f;
      #pragma unroll
      for (int k=0;k<10;k++){ ex[k] = __expf(uw[k]-mx); ss += ex[k]; }
      float inv = 1.0f/ss;
      cumw[0] = -5.f; float cw = 0.f;
      #pragma unroll
      for (int k=0;k<10;k++){ float wk = 0.001f + 0.99f*(ex[k]*inv); cw += wk; cumw[k+1] = 10.f*cw - 5.f; }
      cumw[10] = 5.f;
    }
    {
      float mx = uh[0];
      #pragma unroll
      for (int k=1;k<10;k++) mx = fmaxf(mx, uh[k]);
      float ex[10]; float ss = 0.f;
      #pragma unroll
      for (int k=0;k<10;k++){ ex[k] = __expf(uh[k]-mx); ss += ex[k]; }
      float inv = 1.0f/ss;
      cumh[0] = -5.f; float ch = 0.f;
      #pragma unroll
      for (int k=0;k<10;k++){ float hk = 0.001f + 0.99f*(ex[k]*inv); ch += hk; cumh[k+1] = 10.f*ch - 5.f; }
      cumh[10] = 5.f;
    }
    float dv[11];
    dv[0] = 1.0f; dv[10] = 1.0f;
    #pragma unroll
    for (int k=0;k<9;k++){
      float u = ud9[k];
      float sp = (u > 15.f) ? u : log1pf(__expf(u));
      dv[k+1] = 0.001f + sp;
    }

    const float x1 = x[(b*2+1)*TT_ + tg];
    const float xin = fminf(fmaxf(x1, -5.f), 5.f);
    int cnt = 0;
    #pragma unroll
    for (int k=0;k<11;k++){
      float lk = cumw[k] + ((k==10) ? 1e-6f : 0.f);
      cnt += (xin >= lk) ? 1 : 0;
    }
    int bin = cnt - 1;
    bin = (bin < 0) ? 0 : ((bin > 9) ? 9 : bin);

    float icw=0.f, iw=1.f, ich=0.f, ih=1.f, dl=1.f, dr=1.f;
    #pragma unroll
    for (int k=0;k<10;k++){
      if (bin == k){
        icw = cumw[k]; iw = cumw[k+1]-cumw[k];
        ich = cumh[k]; ih = cumh[k+1]-cumh[k];
        dl = dv[k]; dr = dv[k+1];
      }
    }
    float delta = ih/iw;
    float th = (xin - icw)/iw;
    float t1m = th*(1.f-th);
    float num = ih*(delta*th*th + dl*t1m);
    float den = delta + (dl + dr - 2.f*delta)*t1m;
    float yv = ich + num/den;
    float omt = 1.f - th;
    float dnum = delta*delta*(dr*th*th + 2.f*delta*t1m + dl*omt*omt);
    float lad = logf(dnum) - 2.f*logf(den);
    bool inside = (x1 >= -5.f) && (x1 <= 5.f);
    float outv = inside ? yv : x1;
    float ladv = inside ? lad : 0.f;

    out[(b*2)*TT_ + tg]   = x[(b*2)*TT_ + tg] * msk;
    out[(b*2+1)*TT_ + tg] = outv * msk;

    float lsum = ladv * msk;
    #pragma unroll
    for (int off = 32; off > 0; off >>= 1) lsum += __shfl_xor(lsum, off);
    if (tid == 0) part[b*64 + tile] = lsum;
  }
}

// ---- pre-pass: convert pw_w / proj_w to bf16 in workspace
__global__ void convflow_pre(const float* __restrict__ pw_w, const float* __restrict__ proj_w,
                             short* __restrict__ Wbf, short* __restrict__ Pbf){
  int idx = blockIdx.x*256 + threadIdx.x;
  if (idx < 110592) Wbf[idx] = f2bf(pw_w[idx]);
  if (idx < 32*192){
    int m = idx / 192, k = idx - m*192;
    Pbf[idx] = (m < 29) ? f2bf(proj_w[m*192 + k]) : (short)0;
  }
}

// ---- logdet reduction: 64 tiles per batch
__global__ void convflow_logdet(const float* __restrict__ part, float* __restrict__ out){
  int bb = threadIdx.x;
  if (bb < 64){
    float s = 0.f;
    for (int k=0;k<64;k++) s += part[bb*64 + k];
    out[524288 + bb] = s;
  }
}

extern "C" void kernel_launch(void* const* d_in, const int* in_sizes, int n_in,
                              void* d_out, int out_size, void* d_ws, size_t ws_size,
                              hipStream_t stream) {
  const float* x      = (const float*)d_in[0];
  const float* xmask  = (const float*)d_in[1];
  const float* pre_w  = (const float*)d_in[2];
  const float* pre_b  = (const float*)d_in[3];
  const float* sep_w  = (const float*)d_in[4];
  const float* sep_b  = (const float*)d_in[5];
  const float* pw_w   = (const float*)d_in[6];
  const float* pw_b   = (const float*)d_in[7];
  const float* ln1_g  = (const float*)d_in[8];
  const float* ln1_b  = (const float*)d_in[9];
  const float* ln2_g  = (const float*)d_in[10];
  const float* ln2_b  = (const float*)d_in[11];
  const float* proj_w = (const float*)d_in[12];
  const float* proj_b = (const float*)d_in[13];

  short* Wbf = (short*)d_ws;                              // 3*192*192 bf16
  short* Pbf = (short*)((char*)d_ws + 221184);            // 32*192 bf16
  float* part = (float*)((char*)d_ws + 233472);           // 4096 floats
  float* out = (float*)d_out;

  convflow_pre<<<432, 256, 0, stream>>>(pw_w, proj_w, Wbf, Pbf);
  dim3 grid(64, 64);  // (tile, batch)
  convflow_main<<<grid, NT_, 0, stream>>>(x, xmask, pre_w, pre_b, sep_w, sep_b, pw_b,
                                          ln1_g, ln1_b, ln2_g, ln2_b, proj_b,
                                          Wbf, Pbf, out, part);
  convflow_logdet<<<1, 64, 0, stream>>>(part, out);
}

// Round 4
// 601.238 us; speedup vs baseline: 1.5935x; 1.5935x over previous
//
#include <hip/hip_runtime.h>
#include <stdint.h>

#define TT_ 4096
#define CC_ 192
#define TILE_ 64
#define HALO_ 13
#define TW_ 90
#define HS_ 104     // H row stride (bf16)
#define YTS_ 200    // YT row stride (bf16)
#define NT_ 512

typedef float f32x4 __attribute__((ext_vector_type(4)));
typedef short s16x4 __attribute__((ext_vector_type(4)));
typedef short s16x8 __attribute__((ext_vector_type(8)));
typedef uint32_t ui32x4 __attribute__((ext_vector_type(4)));

__device__ __forceinline__ float bf2f(short s){
  uint32_t u = ((uint32_t)(uint16_t)s) << 16;
  float f; __builtin_memcpy(&f, &u, 4); return f;
}
__device__ __forceinline__ float bfhalf(uint32_t u, int hi){
  uint32_t v = hi ? (u & 0xFFFF0000u) : (u << 16);
  float f; __builtin_memcpy(&f, &v, 4); return f;
}
__device__ __forceinline__ short f2bf(float f){
  uint32_t u; __builtin_memcpy(&u, &f, 4);
  u += 0x7FFFu + ((u >> 16) & 1u);   // RNE
  return (short)(u >> 16);
}
// tanh-form GELU: x*sigmoid(1.5957691*(x+0.044715*x^3))
__device__ __forceinline__ float gelu_f(float x){
  float t = x*x;
  float p = x*__builtin_fmaf(t, 0.0713548162f, 1.5957691216f);
  float e = __expf(-p);
  return x * __builtin_amdgcn_rcpf(1.0f + e);
}

// ---- depthwise conv, transposed write: H[c][j] (bf16, pre-masked) -> YT[j][c]
template<int D>
__device__ __forceinline__ void dw_pass(const short* __restrict__ Hs, short* __restrict__ YTs,
    const float* __restrict__ sw, const float* __restrict__ sb,
    int jlo, int jhi, int tid){
  constexpr int WO = (D==9) ? 16 : 8;
  constexpr int NW = (D==9) ? 5 : 3;   // s16x8 window loads per channel row
  for (int g = tid; g < 96*12; g += NT_){
    int cg = g % 96, jg = g / 96;
    int j0 = jg*8;
    if (j0 + 8 <= jlo || j0 >= jhi) continue;
    int c0 = cg*2;
    uint32_t pk[8];
    #pragma unroll
    for (int cc = 0; cc < 2; ++cc){
      int c = c0 + cc;
      float w0 = sw[c*3+0], w1 = sw[c*3+1], w2 = sw[c*3+2], bb = sb[c];
      uint32_t wp[NW*4];
      const uint32_t* hrow = (const uint32_t*)(Hs + c*HS_ + j0 - WO);  // 16B aligned
      #pragma unroll
      for (int u = 0; u < NW; ++u){
        ui32x4 t = *(const ui32x4*)(hrow + u*4);
        wp[u*4+0]=t[0]; wp[u*4+1]=t[1]; wp[u*4+2]=t[2]; wp[u*4+3]=t[3];
      }
      #pragma unroll
      for (int j = 0; j < 8; ++j){
        float t0 = bfhalf(wp[(WO+j-D)>>1], (WO+j-D)&1);
        float t1 = bfhalf(wp[(WO+j)>>1],   (WO+j)&1);
        float t2 = bfhalf(wp[(WO+j+D)>>1], (WO+j+D)&1);
        float v = __builtin_fmaf(w0,t0, __builtin_fmaf(w1,t1, __builtin_fmaf(w2,t2, bb)));
        uint32_t hb = (uint32_t)(uint16_t)f2bf(v);
        if (cc==0) pk[j] = hb; else pk[j] |= (hb << 16);
      }
    }
    #pragma unroll
    for (int j = 0; j < 8; ++j)
      *(uint32_t*)(YTs + (j0+j)*YTS_ + c0) = pk[j];   // lanes: c fastest -> conflict-free
  }
}

// ---- per-time-row LN stats over 192 cols of YT; 4 threads/row, quad shuffle
__device__ __forceinline__ void ln_stats(const short* __restrict__ YTs, float* __restrict__ SM,
                                         float* __restrict__ SR, int jlo, int jhi, int tid){
  if (tid < 384){
    int row = tid >> 2, qtr = tid & 3;
    if (row >= jlo && row < jhi){
      const short* yr = YTs + row*YTS_ + qtr*48;
      float s0 = 0.f, s1 = 0.f, q0 = 0.f, q1 = 0.f;
      #pragma unroll
      for (int u=0;u<6;++u){
        s16x8 v = *(const s16x8*)(yr + u*8);
        #pragma unroll
        for (int e=0;e<4;e++){ float f=bf2f(v[e]); s0 += f; q0 = __builtin_fmaf(f,f,q0); }
        #pragma unroll
        for (int e=4;e<8;e++){ float f=bf2f(v[e]); s1 += f; q1 = __builtin_fmaf(f,f,q1); }
      }
      float s = s0+s1, q = q0+q1;
      s += __shfl_xor(s,1); q += __shfl_xor(q,1);
      s += __shfl_xor(s,2); q += __shfl_xor(q,2);
      if (qtr==0){
        float mean = s*(1.f/192.f);
        float var = fmaxf(q*(1.f/192.f) - mean*mean, 0.f);
        SM[row]=mean; SR[row]=rsqrtf(var+1e-5f);
      }
    }
  }
}

__global__ __launch_bounds__(512, 4)
void convflow_main(
    const float* __restrict__ x, const float* __restrict__ xmask,
    const float* __restrict__ pre_w, const float* __restrict__ pre_b,
    const float* __restrict__ sep_w, const float* __restrict__ sep_b,
    const float* __restrict__ pw_b,
    const float* __restrict__ ln1_g, const float* __restrict__ ln1_b,
    const float* __restrict__ ln2_g, const float* __restrict__ ln2_b,
    const float* __restrict__ proj_b,
    const short* __restrict__ Wbf, const short* __restrict__ Pbf,
    float* __restrict__ out, float* __restrict__ part)
{
  __shared__ __align__(16) char smem_raw[80128];
  float* MB = (float*)(smem_raw + 0);        // [160]: mask at idx j+16, zero outside valid t
  float* XB = (float*)(smem_raw + 640);      // [96]
  float* SM = (float*)(smem_raw + 1024);     // [96]
  float* SR = (float*)(smem_raw + 1408);     // [96]
  short* H  = (short*)(smem_raw + 1792);     // [192][104] bf16, pre-masked
  short* YT = (short*)(smem_raw + 41728);    // [96][200] bf16 (dw-out / LN1-out / GEMM-out)
  float* HP = (float*)(smem_raw + 67328);    // alias YT rows 64..95: [64][33] proj out

  const int tid = threadIdx.x;
  const int b = blockIdx.y, tile = blockIdx.x;
  const int t0 = tile*TILE_ - HALO_;

  // ---- setup mask + x0 window
  for (int idx = tid; idx < 160; idx += NT_){
    int j = idx - 16; int t = t0 + j;
    float m = 0.f;
    if (j >= 0 && j < TW_ && t >= 0 && t < TT_) m = xmask[b*TT_ + t];
    MB[idx] = m;
  }
  if (tid < 96){
    int t = t0 + tid; float v = 0.f;
    if (tid < TW_ && t >= 0 && t < TT_) v = x[(b*2)*TT_ + t];
    XB[tid] = v;
  }
  __syncthreads();

  // ---- h0 = (pre_w*x0 + pre_b)*mask -> H bf16
  for (int g = tid; g < CC_*12; g += NT_){
    int jq = g % 12, c = g / 12;
    float w = pre_w[c], bb = pre_b[c];
    s16x8 hv;
    #pragma unroll
    for (int e=0;e<8;e++){
      int j = jq*8 + e;
      hv[e] = f2bf((w*XB[j] + bb)*MB[16+j]);
    }
    *(s16x8*)(H + c*HS_ + jq*8) = hv;
  }
  __syncthreads();

  // ---- 3 WN layers
  #pragma unroll 1
  for (int li = 0; li < 3; ++li){
    const int jlo = (li==0) ? 1 : ((li==1) ? 4 : 13);
    const int jhi = (li==0) ? 89 : ((li==1) ? 86 : 77);
    const float* sw = sep_w + li*CC_*3;
    const float* sb = sep_b + li*CC_;

    if (li == 0)      dw_pass<1>(H, YT, sw, sb, jlo, jhi, tid);
    else if (li == 1) dw_pass<3>(H, YT, sw, sb, jlo, jhi, tid);
    else              dw_pass<9>(H, YT, sw, sb, jlo, jhi, tid);
    __syncthreads();

    ln_stats(YT, SM, SR, jlo, jhi, tid); __syncthreads();

    // ---- LN1 + gelu in place on YT rows; zero invalid rows
    {
      const float* g1 = ln1_g + li*CC_;
      const float* b1 = ln1_b + li*CC_;
      for (int g = tid; g < 96*24; g += NT_){
        int ch = g % 24, row = g / 24;
        short* p = YT + row*YTS_ + ch*8;
        if (row >= jlo && row < jhi){
          float m = SM[row], r = SR[row];
          s16x8 v = *(s16x8*)p;
          f32x4 ga = *(const f32x4*)&g1[ch*8], gb = *(const f32x4*)&g1[ch*8+4];
          f32x4 ba = *(const f32x4*)&b1[ch*8], bb = *(const f32x4*)&b1[ch*8+4];
          s16x8 o;
          #pragma unroll
          for (int e=0;e<4;e++){
            float val = (bf2f(v[e]) - m)*r*ga[e] + ba[e];
            o[e] = f2bf(gelu_f(val));
          }
          #pragma unroll
          for (int e=4;e<8;e++){
            float val = (bf2f(v[e]) - m)*r*gb[e-4] + bb[e-4];
            o[e] = f2bf(gelu_f(val));
          }
          *(s16x8*)p = o;
        } else {
          s16x8 z = {0,0,0,0,0,0,0,0};
          *(s16x8*)p = z;
        }
      }
    }
    __syncthreads();

    // ---- pointwise 192x192 GEMM in place on YT: 8 waves = (4 M-thirds x 2 N-halves), 3x3 tiles each
    {
      int w = tid >> 6, lane = tid & 63, l16 = lane & 15, q = lane >> 4;
      int Mh = w & 3, Nh = w >> 2;
      f32x4 acc[3][3];
      #pragma unroll
      for (int r=0;r<3;r++)
        #pragma unroll
        for (int s=0;s<3;s++){ f32x4 z = {0.f,0.f,0.f,0.f}; acc[r][s] = z; }
      const short* Wl = Wbf + li*CC_*CC_;
      #pragma unroll
      for (int kk=0;kk<6;++kk){
        s16x8 bv[3], av[3];
        #pragma unroll
        for (int s=0;s<3;++s)
          bv[s] = *(const s16x8*)&YT[((Nh*3+s)*16 + l16)*YTS_ + kk*32 + q*8];
        #pragma unroll
        for (int r=0;r<3;++r)
          av[r] = *(const s16x8*)&Wl[((Mh*3+r)*16 + l16)*CC_ + kk*32 + q*8];
        #pragma unroll
        for (int r=0;r<3;++r)
          #pragma unroll
          for (int s=0;s<3;++s)
            acc[r][s] = __builtin_amdgcn_mfma_f32_16x16x32_bf16(av[r], bv[s], acc[r][s], 0, 0, 0);
      }
      __syncthreads();   // all B reads complete before in-place writes
      #pragma unroll
      for (int r=0;r<3;++r){
        int m0 = (Mh*3+r)*16 + q*4;
        f32x4 bias = *(const f32x4*)&pw_b[li*CC_ + m0];
        #pragma unroll
        for (int s=0;s<3;++s){
          int n = (Nh*3+s)*16 + l16;
          s16x4 ov;
          #pragma unroll
          for (int e=0;e<4;e++) ov[e] = f2bf(acc[r][s][e] + bias[e]);
          *(s16x4*)(YT + n*YTS_ + m0) = ov;
        }
      }
      __syncthreads();
    }

    ln_stats(YT, SM, SR, jlo, jhi, tid); __syncthreads();

    // ---- LN2 + gelu + residual into H (bf16), restricted to [jlo,jhi)
    {
      const float* g2 = ln2_g + li*CC_;
      const float* b2 = ln2_b + li*CC_;
      for (int g = tid; g < 24*48; g += NT_){
        int cgp = g % 48, jg = g / 48;
        int j0 = jg*4, c0 = cgp*4;
        if (j0 + 4 <= jlo || j0 >= jhi) continue;
        f32x4 mv = *(f32x4*)&SM[j0], rv = *(f32x4*)&SR[j0];
        f32x4 mk = *(f32x4*)&MB[16 + j0];
        f32x4 gv = *(const f32x4*)&g2[c0], bv = *(const f32x4*)&b2[c0];
        s16x4 yr[4];
        #pragma unroll
        for (int jj=0;jj<4;++jj) yr[jj] = *(s16x4*)(YT + (j0+jj)*YTS_ + c0);
        #pragma unroll
        for (int cc=0;cc<4;++cc){
          short* hp_ = H + (c0+cc)*HS_ + j0;
          s16x4 hv = *(s16x4*)hp_;
          s16x4 ho;
          #pragma unroll
          for (int jj=0;jj<4;++jj){
            int j = j0 + jj;
            float val = (bf2f(yr[jj][cc]) - mv[jj])*rv[jj]*gv[cc] + bv[cc];
            float hn = (bf2f(hv[jj]) + gelu_f(val))*mk[jj];
            bool ok = (j >= jlo) && (j < jhi);
            ho[jj] = ok ? f2bf(hn) : hv[jj];
          }
          *(s16x4*)hp_ = ho;
        }
      }
    }
    __syncthreads();
  }

  // ---- proj GEMM (32x192 @ 192x64): A from Pbf, B read directly from H columns
  {
    int w = tid >> 6;
    if (w < 4){
      int lane = tid & 63, l16 = lane & 15, q = lane >> 4;
      int mt = w >> 1, ntp = w & 1;
      f32x4 pacc[2];
      { f32x4 z = {0.f,0.f,0.f,0.f}; pacc[0] = z; pacc[1] = z; }
      #pragma unroll
      for (int kk=0;kk<6;++kk){
        s16x8 a = *(const s16x8*)&Pbf[(mt*16 + l16)*CC_ + kk*32 + q*8];
        #pragma unroll
        for (int s=0;s<2;++s){
          int n = (ntp*2+s)*16 + l16;
          s16x8 bvv;
          #pragma unroll
          for (int i=0;i<8;++i)
            bvv[i] = H[(kk*32 + q*8 + i)*HS_ + HALO_ + n];
          pacc[s] = __builtin_amdgcn_mfma_f32_16x16x32_bf16(a, bvv, pacc[s], 0, 0, 0);
        }
      }
      #pragma unroll
      for (int s=0;s<2;++s)
        #pragma unroll
        for (int e=0;e<4;e++){
          int m = mt*16 + q*4 + e;
          if (m < 29){
            int n = (ntp*2+s)*16 + l16;
            HP[n*33 + m] = (pacc[s][e] + proj_b[m]) * MB[16 + HALO_ + n];
          }
        }
    }
  }
  __syncthreads();

  // ---- rational-quadratic spline, one thread per t
  if (tid < 64){
    const int n = tid;
    const int tg = tile*TILE_ + n;
    const float msk = MB[16 + HALO_ + n];
    const float* hp = &HP[n*33];
    const float inv_s = 0.07216878364870323f;  // 1/sqrt(192)
    float uw[10], uh[10], ud9[9];
    #pragma unroll
    for (int k=0;k<10;k++){ uw[k] = hp[k]*inv_s; uh[k] = hp[10+k]*inv_s; }
    #pragma unroll
    for (int k=0;k<9;k++) ud9[k] = hp[20+k];

    float cumw[11], cumh[11];
    {
      float mx = uw[0];
      #pragma unroll
      for (int k=1;k<10;k++) mx = fmaxf(mx, uw[k]);
      float ex[10]; float ss = 0.f;
      #pragma unroll
      for (int k=0;k<10;k++){ ex[k] = __expf(uw[k]-mx); ss += ex[k]; }
      float inv = 1.0f/ss;
      cumw[0] = -5.f; float cw = 0.f;
      #pragma unroll
      for (int k=0;k<10;k++){ float wk = 0.001f + 0.99f*(ex[k]*inv); cw += wk; cumw[k+1] = 10.f*cw - 5.f; }
      cumw[10] = 5.f;
    }
    {
      float mx = uh[0];
      #pragma unroll
      for (int k=1;k<10;k++) mx = fmaxf(mx, uh[k]);
      float ex[10]; float ss = 0.f;
      #pragma unroll
      for (int k=0;k<10;k++){ ex[k] = __expf(uh[k]-mx); ss += ex[k]; }
      float inv = 1.0f/ss;
      cumh[0] = -5.f; float ch = 0.f;
      #pragma unroll
      for (int k=0;k<10;k++){ float hk = 0.001f + 0.99f*(ex[k]*inv); ch += hk; cumh[k+1] = 10.f*ch - 5.f; }
      cumh[10] = 5.f;
    }
    float dv[11];
    dv[0] = 1.0f; dv[10] = 1.0f;
    #pragma unroll
    for (int k=0;k<9;k++){
      float u = ud9[k];
      float sp = (u > 15.f) ? u : log1pf(__expf(u));
      dv[k+1] = 0.001f + sp;
    }

    const float x1 = x[(b*2+1)*TT_ + tg];
    const float xin = fminf(fmaxf(x1, -5.f), 5.f);
    int cnt = 0;
    #pragma unroll
    for (int k=0;k<11;k++){
      float lk = cumw[k] + ((k==10) ? 1e-6f : 0.f);
      cnt += (xin >= lk) ? 1 : 0;
    }
    int bin = cnt - 1;
    bin = (bin < 0) ? 0 : ((bin > 9) ? 9 : bin);

    float icw=0.f, iw=1.f, ich=0.f, ih=1.f, dl=1.f, dr=1.f;
    #pragma unroll
    for (int k=0;k<10;k++){
      if (bin == k){
        icw = cumw[k]; iw = cumw[k+1]-cumw[k];
        ich = cumh[k]; ih = cumh[k+1]-cumh[k];
        dl = dv[k]; dr = dv[k+1];
      }
    }
    float delta = ih/iw;
    float th = (xin - icw)/iw;
    float t1m = th*(1.f-th);
    float num = ih*(delta*th*th + dl*t1m);
    float den = delta + (dl + dr - 2.f*delta)*t1m;
    float yv = ich + num/den;
    float omt = 1.f - th;
    float dnum = delta*delta*(dr*th*th + 2.f*delta*t1m + dl*omt*omt);
    float lad = logf(dnum) - 2.f*logf(den);
    bool inside = (x1 >= -5.f) && (x1 <= 5.f);
    float outv = inside ? yv : x1;
    float ladv = inside ? lad : 0.f;

    out[(b*2)*TT_ + tg]   = x[(b*2)*TT_ + tg] * msk;
    out[(b*2+1)*TT_ + tg] = outv * msk;

    float lsum = ladv * msk;
    #pragma unroll
    for (int off = 32; off > 0; off >>= 1) lsum += __shfl_xor(lsum, off);
    if (tid == 0) part[b*64 + tile] = lsum;
  }
}

// ---- pre-pass: convert pw_w / proj_w to bf16 in workspace
__global__ void convflow_pre(const float* __restrict__ pw_w, const float* __restrict__ proj_w,
                             short* __restrict__ Wbf, short* __restrict__ Pbf){
  int idx = blockIdx.x*256 + threadIdx.x;
  if (idx < 110592) Wbf[idx] = f2bf(pw_w[idx]);
  if (idx < 32*192){
    int m = idx / 192, k = idx - m*192;
    Pbf[idx] = (m < 29) ? f2bf(proj_w[m*192 + k]) : (short)0;
  }
}

// ---- logdet reduction: 64 tiles per batch
__global__ void convflow_logdet(const float* __restrict__ part, float* __restrict__ out){
  int bb = threadIdx.x;
  if (bb < 64){
    float s = 0.f;
    for (int k=0;k<64;k++) s += part[bb*64 + k];
    out[524288 + bb] = s;
  }
}

extern "C" void kernel_launch(void* const* d_in, const int* in_sizes, int n_in,
                              void* d_out, int out_size, void* d_ws, size_t ws_size,
                              hipStream_t stream) {
  const float* x      = (const float*)d_in[0];
  const float* xmask  = (const float*)d_in[1];
  const float* pre_w  = (const float*)d_in[2];
  const float* pre_b  = (const float*)d_in[3];
  const float* sep_w  = (const float*)d_in[4];
  const float* sep_b  = (const float*)d_in[5];
  const float* pw_w   = (const float*)d_in[6];
  const float* pw_b   = (const float*)d_in[7];
  const float* ln1_g  = (const float*)d_in[8];
  const float* ln1_b  = (const float*)d_in[9];
  const float* ln2_g  = (const float*)d_in[10];
  const float* ln2_b  = (const float*)d_in[11];
  const float* proj_w = (const float*)d_in[12];
  const float* proj_b = (const float*)d_in[13];

  short* Wbf = (short*)d_ws;                              // 3*192*192 bf16
  short* Pbf = (short*)((char*)d_ws + 221184);            // 32*192 bf16
  float* part = (float*)((char*)d_ws + 233472);           // 4096 floats
  float* out = (float*)d_out;

  convflow_pre<<<432, 256, 0, stream>>>(pw_w, proj_w, Wbf, Pbf);
  dim3 grid(64, 64);  // (tile, batch)
  convflow_main<<<grid, NT_, 0, stream>>>(x, xmask, pre_w, pre_b, sep_w, sep_b, pw_b,
                                          ln1_g, ln1_b, ln2_g, ln2_b, proj_b,
                                          Wbf, Pbf, out, part);
  convflow_logdet<<<1, 64, 0, stream>>>(part, out);
}

// Round 5
// 595.500 us; speedup vs baseline: 1.6089x; 1.0096x over previous
//
#include <hip/hip_runtime.h>
#include <stdint.h>

#define TT_ 4096
#define CC_ 192
#define TILE_ 64
#define HALO_ 13
#define TW_ 90
#define HS_ 100     // H row stride (shorts) -> 50 dwords; 2 rows = 100 dw = 4 mod 32 (spread)
#define YTS_ 200    // YT row stride (shorts) = 100 dwords
#define NT_ 512

typedef float f32x4 __attribute__((ext_vector_type(4)));
typedef short s16x4 __attribute__((ext_vector_type(4)));
typedef short s16x8 __attribute__((ext_vector_type(8)));
typedef uint32_t ui32x2 __attribute__((ext_vector_type(2)));
typedef uint32_t ui32x4 __attribute__((ext_vector_type(4)));

__device__ __forceinline__ float bf2f(short s){
  uint32_t u = ((uint32_t)(uint16_t)s) << 16;
  float f; __builtin_memcpy(&f, &u, 4); return f;
}
__device__ __forceinline__ float bfhalf(uint32_t u, int hi){
  uint32_t v = hi ? (u & 0xFFFF0000u) : (u << 16);
  float f; __builtin_memcpy(&f, &v, 4); return f;
}
__device__ __forceinline__ short f2bf(float f){
  uint32_t u; __builtin_memcpy(&u, &f, 4);
  u += 0x7FFFu + ((u >> 16) & 1u);   // RNE
  return (short)(u >> 16);
}
__device__ __forceinline__ uint32_t fbits(float f){
  uint32_t u; __builtin_memcpy(&u, &f, 4); return u;
}
// pack two f32 -> two bf16 (TRUNCATE) in ONE v_perm_b32. low16 = lo, high16 = hi.
__device__ __forceinline__ uint32_t pk_trunc(float lo, float hi){
  return __builtin_amdgcn_perm(fbits(hi), fbits(lo), 0x07060302u);
}
__device__ __forceinline__ uint32_t rne_u(float f){
  uint32_t u = fbits(f);
  return u + 0x7FFFu + ((u >> 16) & 1u);
}
// pack two f32 -> two bf16 (RNE): 2x3 ops + 1 perm
__device__ __forceinline__ uint32_t pk_rne(float lo, float hi){
  return __builtin_amdgcn_perm(rne_u(hi), rne_u(lo), 0x07060302u);
}
// tanh-form GELU: x*sigmoid(1.5957691*(x+0.044715*x^3))
__device__ __forceinline__ float gelu_f(float x){
  float t = x*x;
  float p = x*__builtin_fmaf(t, 0.0713548162f, 1.5957691216f);
  float e = __expf(-p);
  return x * __builtin_amdgcn_rcpf(1.0f + e);
}
// YT granule swizzle: 16B granule g of row r stored at g ^ (r&3). Spreads GEMM
// B-reads (lane l16 reads granule q^(l16&3)) to the uniform-8 bank floor.
__device__ __forceinline__ int ytix(int row, int col){
  return row*YTS_ + ((((col >> 3) ^ (row & 3)) << 3) | (col & 7));
}

// ---- depthwise conv, transposed write: H[c][j] (bf16, pre-masked) -> YT[j][c]
template<int D>
__device__ __forceinline__ void dw_pass(const short* __restrict__ Hs, short* __restrict__ YTs,
    const float* __restrict__ sw, const float* __restrict__ sb,
    int jlo, int jhi, int tid){
  constexpr int WO = (D==9) ? 16 : 8;   // window back-offset (shorts)
  constexpr int NU = (D==9) ? 20 : 12;  // uint32 window words per row
  for (int g = tid; g < 96*12; g += NT_){
    int cg = g % 96, jg = g / 96;
    int j0 = jg*8;
    if (j0 + 8 <= jlo || j0 >= jhi) continue;
    int c0 = cg*2;
    uint32_t wpa[NU], wpb[NU];
    {
      const uint32_t* ra = (const uint32_t*)(Hs + (c0+0)*HS_ + j0 - WO);
      const uint32_t* rb = (const uint32_t*)(Hs + (c0+1)*HS_ + j0 - WO);
      #pragma unroll
      for (int u = 0; u < NU/2; ++u){
        ui32x2 ta = *(const ui32x2*)(ra + u*2);
        ui32x2 tb = *(const ui32x2*)(rb + u*2);
        wpa[u*2] = ta[0]; wpa[u*2+1] = ta[1];
        wpb[u*2] = tb[0]; wpb[u*2+1] = tb[1];
      }
    }
    float w0a = sw[c0*3+0], w1a = sw[c0*3+1], w2a = sw[c0*3+2], bav = sb[c0];
    float w0b = sw[c0*3+3], w1b = sw[c0*3+4], w2b = sw[c0*3+5], bbv = sb[c0+1];
    #pragma unroll
    for (int j = 0; j < 8; ++j){
      int h0 = WO + j - D, h1 = WO + j, h2 = WO + j + D;
      float va = __builtin_fmaf(w0a, bfhalf(wpa[h0>>1], h0&1),
                 __builtin_fmaf(w1a, bfhalf(wpa[h1>>1], h1&1),
                 __builtin_fmaf(w2a, bfhalf(wpa[h2>>1], h2&1), bav)));
      float vb = __builtin_fmaf(w0b, bfhalf(wpb[h0>>1], h0&1),
                 __builtin_fmaf(w1b, bfhalf(wpb[h1>>1], h1&1),
                 __builtin_fmaf(w2b, bfhalf(wpb[h2>>1], h2&1), bbv)));
      *(uint32_t*)(YTs + ytix(j0+j, c0)) = pk_trunc(va, vb);  // trunc: LN1 follows
    }
  }
}

// ---- per-time-row LN stats over 192 cols of YT; 4 threads/row, quad shuffle
__device__ __forceinline__ void ln_stats(const short* __restrict__ YTs, float* __restrict__ SM,
                                         float* __restrict__ SR, int jlo, int jhi, int tid){
  if (tid < 384){
    int row = tid >> 2, qtr = tid & 3;
    if (row >= jlo && row < jhi){
      float s0 = 0.f, s1 = 0.f, q0 = 0.f, q1 = 0.f;
      #pragma unroll
      for (int u=0;u<6;++u){
        s16x8 v = *(const s16x8*)(YTs + ytix(row, qtr*48 + u*8));
        #pragma unroll
        for (int e=0;e<4;e++){ float f=bf2f(v[e]); s0 += f; q0 = __builtin_fmaf(f,f,q0); }
        #pragma unroll
        for (int e=4;e<8;e++){ float f=bf2f(v[e]); s1 += f; q1 = __builtin_fmaf(f,f,q1); }
      }
      float s = s0+s1, q = q0+q1;
      s += __shfl_xor(s,1); q += __shfl_xor(q,1);
      s += __shfl_xor(s,2); q += __shfl_xor(q,2);
      if (qtr==0){
        float mean = s*(1.f/192.f);
        float var = fmaxf(q*(1.f/192.f) - mean*mean, 0.f);
        SM[row]=mean; SR[row]=rsqrtf(var+1e-5f);
      }
    }
  }
}

__global__ __launch_bounds__(512, 4)
void convflow_main(
    const float* __restrict__ x, const float* __restrict__ xmask,
    const float* __restrict__ pre_w, const float* __restrict__ pre_b,
    const float* __restrict__ sep_w, const float* __restrict__ sep_b,
    const float* __restrict__ pw_b,
    const float* __restrict__ ln1_g, const float* __restrict__ ln1_b,
    const float* __restrict__ ln2_g, const float* __restrict__ ln2_b,
    const float* __restrict__ proj_b,
    const short* __restrict__ Wbf, const short* __restrict__ Pbf,
    float* __restrict__ out, float* __restrict__ part)
{
  __shared__ __align__(16) char smem_raw[78592];
  float* MB = (float*)(smem_raw + 0);        // [160]: mask at idx j+16, zero outside valid t
  float* XB = (float*)(smem_raw + 640);      // [96]
  float* SM = (float*)(smem_raw + 1024);     // [96]
  float* SR = (float*)(smem_raw + 1408);     // [96]
  short* H  = (short*)(smem_raw + 1792);     // [192][100] bf16, pre-masked
  short* YT = (short*)(smem_raw + 40192);    // [96][200] bf16, granule-swizzled
  float* HP = (float*)(smem_raw + 65792);    // alias YT rows 64..95: [64][33] proj out

  const int tid = threadIdx.x;
  const int b = blockIdx.y, tile = blockIdx.x;
  const int t0 = tile*TILE_ - HALO_;

  // ---- setup mask + x0 window
  for (int idx = tid; idx < 160; idx += NT_){
    int j = idx - 16; int t = t0 + j;
    float m = 0.f;
    if (j >= 0 && j < TW_ && t >= 0 && t < TT_) m = xmask[b*TT_ + t];
    MB[idx] = m;
  }
  if (tid < 96){
    int t = t0 + tid; float v = 0.f;
    if (tid < TW_ && t >= 0 && t < TT_) v = x[(b*2)*TT_ + t];
    XB[tid] = v;
  }
  __syncthreads();

  // ---- h0 = (pre_w*x0 + pre_b)*mask -> H bf16 (RNE: H feeds proj w/o LN)
  for (int g = tid; g < CC_*24; g += NT_){
    int jq = g % 24, c = g / 24;
    float w = pre_w[c], bb = pre_b[c];
    int j0 = jq*4;
    float v0 = (w*XB[j0+0] + bb)*MB[16+j0+0];
    float v1 = (w*XB[j0+1] + bb)*MB[16+j0+1];
    float v2 = (w*XB[j0+2] + bb)*MB[16+j0+2];
    float v3 = (w*XB[j0+3] + bb)*MB[16+j0+3];
    ui32x2 o; o[0] = pk_rne(v0, v1); o[1] = pk_rne(v2, v3);
    *(ui32x2*)(H + c*HS_ + j0) = o;
  }
  __syncthreads();

  // ---- 3 WN layers
  #pragma unroll 1
  for (int li = 0; li < 3; ++li){
    const int jlo = (li==0) ? 1 : ((li==1) ? 4 : 13);
    const int jhi = (li==0) ? 89 : ((li==1) ? 86 : 77);
    const float* sw = sep_w + li*CC_*3;
    const float* sb = sep_b + li*CC_;

    if (li == 0)      dw_pass<1>(H, YT, sw, sb, jlo, jhi, tid);
    else if (li == 1) dw_pass<3>(H, YT, sw, sb, jlo, jhi, tid);
    else              dw_pass<9>(H, YT, sw, sb, jlo, jhi, tid);
    __syncthreads();

    ln_stats(YT, SM, SR, jlo, jhi, tid); __syncthreads();

    // ---- LN1 + gelu in place on YT rows; zero invalid rows (trunc: LN2 follows)
    {
      const float* g1 = ln1_g + li*CC_;
      const float* b1 = ln1_b + li*CC_;
      for (int g = tid; g < 96*24; g += NT_){
        int ch = g % 24, row = g / 24;
        short* p = YT + ytix(row, ch*8);
        if (row >= jlo && row < jhi){
          float m = SM[row], r = SR[row];
          s16x8 v = *(s16x8*)p;
          f32x4 ga = *(const f32x4*)&g1[ch*8], gb = *(const f32x4*)&g1[ch*8+4];
          f32x4 ba = *(const f32x4*)&b1[ch*8], bb = *(const f32x4*)&b1[ch*8+4];
          float ov[8];
          #pragma unroll
          for (int e=0;e<4;e++){
            float val = (bf2f(v[e]) - m)*r*ga[e] + ba[e];
            ov[e] = gelu_f(val);
          }
          #pragma unroll
          for (int e=4;e<8;e++){
            float val = (bf2f(v[e]) - m)*r*gb[e-4] + bb[e-4];
            ov[e] = gelu_f(val);
          }
          ui32x4 o;
          #pragma unroll
          for (int e=0;e<4;e++) o[e] = pk_trunc(ov[2*e], ov[2*e+1]);
          *(ui32x4*)p = o;
        } else {
          ui32x4 z = {0u,0u,0u,0u};
          *(ui32x4*)p = z;
        }
      }
    }
    __syncthreads();

    // ---- pointwise 192x192 GEMM in place on YT: 8 waves = (4 M x 2 N), 3x3 tiles each
    {
      int w = tid >> 6, lane = tid & 63, l16 = lane & 15, q = lane >> 4;
      int Mh = w & 3, Nh = w >> 2;
      f32x4 acc[3][3];
      #pragma unroll
      for (int r=0;r<3;r++)
        #pragma unroll
        for (int s=0;s<3;s++){ f32x4 z = {0.f,0.f,0.f,0.f}; acc[r][s] = z; }
      const short* Wl = Wbf + li*CC_*CC_;
      #pragma unroll
      for (int kk=0;kk<6;++kk){
        s16x8 bv[3], av[3];
        #pragma unroll
        for (int s=0;s<3;++s)
          bv[s] = *(const s16x8*)&YT[ytix((Nh*3+s)*16 + l16, kk*32 + q*8)];
        #pragma unroll
        for (int r=0;r<3;++r)
          av[r] = *(const s16x8*)&Wl[((Mh*3+r)*16 + l16)*CC_ + kk*32 + q*8];
        #pragma unroll
        for (int r=0;r<3;++r)
          #pragma unroll
          for (int s=0;s<3;++s)
            acc[r][s] = __builtin_amdgcn_mfma_f32_16x16x32_bf16(av[r], bv[s], acc[r][s], 0, 0, 0);
      }
      __syncthreads();   // all B reads complete before in-place writes
      #pragma unroll
      for (int r=0;r<3;++r){
        int m0 = (Mh*3+r)*16 + q*4;
        f32x4 bias = *(const f32x4*)&pw_b[li*CC_ + m0];
        #pragma unroll
        for (int s=0;s<3;++s){
          int n = (Nh*3+s)*16 + l16;
          ui32x2 ov;
          ov[0] = pk_trunc(acc[r][s][0]+bias[0], acc[r][s][1]+bias[1]);
          ov[1] = pk_trunc(acc[r][s][2]+bias[2], acc[r][s][3]+bias[3]);
          *(ui32x2*)(YT + ytix(n, m0)) = ov;
        }
      }
      __syncthreads();
    }

    ln_stats(YT, SM, SR, jlo, jhi, tid); __syncthreads();

    // ---- LN2 + gelu + residual into H (RNE: H feeds proj w/o LN)
    {
      const float* g2 = ln2_g + li*CC_;
      const float* b2 = ln2_b + li*CC_;
      for (int g = tid; g < 24*48; g += NT_){
        int cgp = g % 48, jg = g / 48;
        int j0 = jg*4, c0 = cgp*4;
        if (j0 + 4 <= jlo || j0 >= jhi) continue;
        f32x4 mv = *(f32x4*)&SM[j0], rv = *(f32x4*)&SR[j0];
        f32x4 mk = *(f32x4*)&MB[16 + j0];
        f32x4 gv = *(const f32x4*)&g2[c0], bv = *(const f32x4*)&b2[c0];
        s16x4 yr[4];
        #pragma unroll
        for (int jj=0;jj<4;++jj) yr[jj] = *(s16x4*)(YT + ytix(j0+jj, c0));
        #pragma unroll
        for (int cc=0;cc<4;++cc){
          short* hp_ = H + (c0+cc)*HS_ + j0;
          s16x4 hv = *(s16x4*)hp_;
          float hf[4];
          #pragma unroll
          for (int jj=0;jj<4;++jj){
            int j = j0 + jj;
            float val = (bf2f(yr[jj][cc]) - mv[jj])*rv[jj]*gv[cc] + bv[cc];
            float hn = (bf2f(hv[jj]) + gelu_f(val))*mk[jj];
            bool ok = (j >= jlo) && (j < jhi);
            hf[jj] = ok ? hn : bf2f(hv[jj]);   // RNE(bf2f(old)) == old exactly
          }
          ui32x2 o; o[0] = pk_rne(hf[0], hf[1]); o[1] = pk_rne(hf[2], hf[3]);
          *(ui32x2*)hp_ = o;
        }
      }
    }
    __syncthreads();
  }

  // ---- proj GEMM (32x192 @ 192x64): A from Pbf, B read directly from H columns
  {
    int w = tid >> 6;
    if (w < 4){
      int lane = tid & 63, l16 = lane & 15, q = lane >> 4;
      int mt = w >> 1, ntp = w & 1;
      f32x4 pacc[2];
      { f32x4 z = {0.f,0.f,0.f,0.f}; pacc[0] = z; pacc[1] = z; }
      #pragma unroll
      for (int kk=0;kk<6;++kk){
        s16x8 a = *(const s16x8*)&Pbf[(mt*16 + l16)*CC_ + kk*32 + q*8];
        #pragma unroll
        for (int s=0;s<2;++s){
          int n = (ntp*2+s)*16 + l16;
          s16x8 bvv;
          #pragma unroll
          for (int i=0;i<8;++i)
            bvv[i] = H[(kk*32 + q*8 + i)*HS_ + HALO_ + n];
          pacc[s] = __builtin_amdgcn_mfma_f32_16x16x32_bf16(a, bvv, pacc[s], 0, 0, 0);
        }
      }
      #pragma unroll
      for (int s=0;s<2;++s)
        #pragma unroll
        for (int e=0;e<4;e++){
          int m = mt*16 + q*4 + e;
          if (m < 29){
            int n = (ntp*2+s)*16 + l16;
            HP[n*33 + m] = (pacc[s][e] + proj_b[m]) * MB[16 + HALO_ + n];
          }
        }
    }
  }
  __syncthreads();

  // ---- rational-quadratic spline, one thread per t
  if (tid < 64){
    const int n = tid;
    const int tg = tile*TILE_ + n;
    const float msk = MB[16 + HALO_ + n];
    const float* hp = &HP[n*33];
    const float inv_s = 0.07216878364870323f;  // 1/sqrt(192)
    float uw[10], uh[10], ud9[9];
    #pragma unroll
    for (int k=0;k<10;k++){ uw[k] = hp[k]*inv_s; uh[k] = hp[10+k]*inv_s; }
    #pragma unroll
    for (int k=0;k<9;k++) ud9[k] = hp[20+k];

    float cumw[11], cumh[11];
    {
      float mx = uw[0];
      #pragma unroll
      for (int k=1;k<10;k++) mx = fmaxf(mx, uw[k]);
      float ex[10]; float ss = 0.f;
      #pragma unroll
      for (int k=0;k<10;k++){ ex[k] = __expf(uw[k]-mx); ss += ex[k]; }
      float inv = 1.0f/ss;
      cumw[0] = -5.f; float cw = 0.f;
      #pragma unroll
      for (int k=0;k<10;k++){ float wk = 0.001f + 0.99f*(ex[k]*inv); cw += wk; cumw[k+1] = 10.f*cw - 5.f; }
      cumw[10] = 5.f;
    }
    {
      float mx = uh[0];
      #pragma unroll
      for (int k=1;k<10;k++) mx = fmaxf(mx, uh[k]);
      float ex[10]; float ss = 0.f;
      #pragma unroll
      for (int k=0;k<10;k++){ ex[k] = __expf(uh[k]-mx); ss += ex[k]; }
      float inv = 1.0f/ss;
      cumh[0] = -5.f; float ch = 0.f;
      #pragma unroll
      for (int k=0;k<10;k++){ float hk = 0.001f + 0.99f*(ex[k]*inv); ch += hk; cumh[k+1] = 10.f*ch - 5.f; }
      cumh[10] = 5.f;
    }
    float dv[11];
    dv[0] = 1.0f; dv[10] = 1.0f;
    #pragma unroll
    for (int k=0;k<9;k++){
      float u = ud9[k];
      float sp = (u > 15.f) ? u : log1pf(__expf(u));
      dv[k+1] = 0.001f + sp;
    }

    const float x1 = x[(b*2+1)*TT_ + tg];
    const float xin = fminf(fmaxf(x1, -5.f), 5.f);
    int cnt = 0;
    #pragma unroll
    for (int k=0;k<11;k++){
      float lk = cumw[k] + ((k==10) ? 1e-6f : 0.f);
      cnt += (xin >= lk) ? 1 : 0;
    }
    int bin = cnt - 1;
    bin = (bin < 0) ? 0 : ((bin > 9) ? 9 : bin);

    float icw=0.f, iw=1.f, ich=0.f, ih=1.f, dl=1.f, dr=1.f;
    #pragma unroll
    for (int k=0;k<10;k++){
      if (bin == k){
        icw = cumw[k]; iw = cumw[k+1]-cumw[k];
        ich = cumh[k]; ih = cumh[k+1]-cumh[k];
        dl = dv[k]; dr = dv[k+1];
      }
    }
    float delta = ih/iw;
    float th = (xin - icw)/iw;
    float t1m = th*(1.f-th);
    float num = ih*(delta*th*th + dl*t1m);
    float den = delta + (dl + dr - 2.f*delta)*t1m;
    float yv = ich + num/den;
    float omt = 1.f - th;
    float dnum = delta*delta*(dr*th*th + 2.f*delta*t1m + dl*omt*omt);
    float lad = logf(dnum) - 2.f*logf(den);
    bool inside = (x1 >= -5.f) && (x1 <= 5.f);
    float outv = inside ? yv : x1;
    float ladv = inside ? lad : 0.f;

    out[(b*2)*TT_ + tg]   = x[(b*2)*TT_ + tg] * msk;
    out[(b*2+1)*TT_ + tg] = outv * msk;

    float lsum = ladv * msk;
    #pragma unroll
    for (int off = 32; off > 0; off >>= 1) lsum += __shfl_xor(lsum, off);
    if (tid == 0) part[b*64 + tile] = lsum;
  }
}

// ---- pre-pass: convert pw_w / proj_w to bf16 in workspace
__global__ void convflow_pre(const float* __restrict__ pw_w, const float* __restrict__ proj_w,
                             short* __restrict__ Wbf, short* __restrict__ Pbf){
  int idx = blockIdx.x*256 + threadIdx.x;
  if (idx < 110592) Wbf[idx] = f2bf(pw_w[idx]);
  if (idx < 32*192){
    int m = idx / 192, k = idx - m*192;
    Pbf[idx] = (m < 29) ? f2bf(proj_w[m*192 + k]) : (short)0;
  }
}

// ---- logdet reduction: 64 tiles per batch
__global__ void convflow_logdet(const float* __restrict__ part, float* __restrict__ out){
  int bb = threadIdx.x;
  if (bb < 64){
    float s = 0.f;
    for (int k=0;k<64;k++) s += part[bb*64 + k];
    out[524288 + bb] = s;
  }
}

extern "C" void kernel_launch(void* const* d_in, const int* in_sizes, int n_in,
                              void* d_out, int out_size, void* d_ws, size_t ws_size,
                              hipStream_t stream) {
  const float* x      = (const float*)d_in[0];
  const float* xmask  = (const float*)d_in[1];
  const float* pre_w  = (const float*)d_in[2];
  const float* pre_b  = (const float*)d_in[3];
  const float* sep_w  = (const float*)d_in[4];
  const float* sep_b  = (const float*)d_in[5];
  const float* pw_w   = (const float*)d_in[6];
  const float* pw_b   = (const float*)d_in[7];
  const float* ln1_g  = (const float*)d_in[8];
  const float* ln1_b  = (const float*)d_in[9];
  const float* ln2_g  = (const float*)d_in[10];
  const float* ln2_b  = (const float*)d_in[11];
  const float* proj_w = (const float*)d_in[12];
  const float* proj_b = (const float*)d_in[13];

  short* Wbf = (short*)d_ws;                              // 3*192*192 bf16
  short* Pbf = (short*)((char*)d_ws + 221184);            // 32*192 bf16
  float* part = (float*)((char*)d_ws + 233472);           // 4096 floats
  float* out = (float*)d_out;

  convflow_pre<<<432, 256, 0, stream>>>(pw_w, proj_w, Wbf, Pbf);
  dim3 grid(64, 64);  // (tile, batch)
  convflow_main<<<grid, NT_, 0, stream>>>(x, xmask, pre_w, pre_b, sep_w, sep_b, pw_b,
                                          ln1_g, ln1_b, ln2_g, ln2_b, proj_b,
                                          Wbf, Pbf, out, part);
  convflow_logdet<<<1, 64, 0, stream>>>(part, out);
}